// Round 1
// baseline (272.686 us; speedup 1.0000x reference)
//
#include <hip/hip_runtime.h>
#include <math.h>
#include <float.h>

// Problem constants
#define NTOK 65536
#define NCB  4
#define MCODE 512
#define DIM  64

#define QST_SIZE (NTOK * NCB * DIM)        // 16777216
#define IDX_OFF  (QST_SIZE + 3)            // 16777219

// Tiles
#define TOK_TILE  128                      // tokens per block (32 per wave) -> LDS 34.8KB -> 4 blocks/CU
#define NSUB      2                        // 16-row MFMA subtiles per wave
#define XS_STRIDE 68                       // fp32 LDS stride: 68%32=4 -> 2-way alias (free)

// ws layout (bytes):
//   eh  f16[2048*64]  @ 0        (262144)   hi half of 512*e
//   el  f16[2048*64]  @ 262144   (262144)   lo half
//   d0  f32[2048]     @ 524288   (8192)     512 * sum(e^2)
//   counts int[2048]  @ 532480   (8192)
//   lossSum f32       @ 540672
#define WS_EH 0
#define WS_EL 262144
#define WS_D0 524288
#define WS_CNT 532480
#define WS_LOSS 540672

typedef _Float16 half8 __attribute__((ext_vector_type(8)));
typedef float floatx4 __attribute__((ext_vector_type(4)));

// ---- prep: f16 hi/lo split of 512*e, d0 = 512*|e|^2, zero counts/loss ----
__global__ __launch_bounds__(256) void prep_kernel(const float* __restrict__ emb,
                                                   _Float16* __restrict__ eh,
                                                   _Float16* __restrict__ el,
                                                   float* __restrict__ d0,
                                                   int* __restrict__ counts,
                                                   float* __restrict__ lossSum) {
    int row = blockIdx.x * 256 + threadIdx.x;   // 0..2047  (grid=8)
    if (row >= NCB * MCODE) return;
    const float* src = emb + (size_t)row * DIM;
    _Float16* ph = eh + (size_t)row * DIM;
    _Float16* pl = el + (size_t)row * DIM;
    float s = 0.f;
#pragma unroll
    for (int j = 0; j < DIM / 8; ++j) {
        half8 h, l;
#pragma unroll
        for (int t = 0; t < 8; ++t) {
            float e = src[j * 8 + t];
            s += e * e;
            float f = e * 512.0f;
            _Float16 hi = (_Float16)f;
            float r = f - (float)hi;
            h[t] = hi;
            l[t] = (_Float16)r;
        }
        *(half8*)(ph + j * 8) = h;
        *(half8*)(pl + j * 8) = l;
    }
    d0[row] = 512.0f * s;
    counts[row] = 0;
    if (row == 0) *lossSum = 0.f;
}

// ---- main: MFMA distances + argmin + epilogue ----
// block = 256 threads = 4 waves; each wave owns 32 tokens (2 subtiles of 16)
__global__ __launch_bounds__(256, 4) void vq_main(const float* __restrict__ x,
                                                  const float* __restrict__ emb,
                                                  const float* __restrict__ mask,
                                                  const _Float16* __restrict__ eh,
                                                  const _Float16* __restrict__ el,
                                                  const float* __restrict__ d0,
                                                  int* __restrict__ counts,
                                                  float* __restrict__ lossSum,
                                                  float* __restrict__ outQ,
                                                  float* __restrict__ outIdx) {
    __shared__ float Xs[TOK_TILE * XS_STRIDE];   // 34816 B
    __shared__ int   Is[TOK_TILE];
    __shared__ float wls[4];

    const int tid  = threadIdx.x;
    const int c    = blockIdx.y;
    const int n0tk = blockIdx.x * TOK_TILE;
    const int lane = tid & 63;
    const int w    = tid >> 6;            // wave id 0..3
    const int col  = lane & 15;           // MFMA col (code within tile) / row m in A
    const int quad = lane >> 4;           // 0..3

    // ---- stage X tile: 128 tokens x 64 dims fp32, coalesced (2048 float4) ----
#pragma unroll
    for (int i = 0; i < 8; ++i) {
        int q = tid + i * 256;
        int tok = q >> 4, d4 = q & 15;
        float4 v = *(const float4*)(x + (size_t)(n0tk + tok) * (NCB * DIM) + c * DIM + d4 * 4);
        *(float4*)(Xs + tok * XS_STRIDE + d4 * 4) = v;
    }
    __syncthreads();

    // ---- build persistent A fragments (hi/lo) for this wave's 32 tokens ----
    // subtile s: tokens w*32 + s*16 + col ; kstep ks: k = ks*32 + quad*8 + j
    half8 Ahi[NSUB][2], Alo[NSUB][2];
#pragma unroll
    for (int s = 0; s < NSUB; ++s) {
        const float* xr = Xs + (w * 32 + s * 16 + col) * XS_STRIDE;
#pragma unroll
        for (int ks = 0; ks < 2; ++ks) {
            const float* p = xr + ks * 32 + quad * 8;
            half8 h, l;
#pragma unroll
            for (int t = 0; t < 8; ++t) {
                float f = p[t];
                _Float16 hi = (_Float16)f;
                float r = f - (float)hi;
                h[t] = hi;
                l[t] = (_Float16)r;
            }
            Ahi[s][ks] = h;
            Alo[s][ks] = l;
        }
    }

    float minv[NSUB][4];
    int   mini[NSUB][4];
#pragma unroll
    for (int s = 0; s < NSUB; ++s)
#pragma unroll
        for (int r = 0; r < 4; ++r) { minv[s][r] = FLT_MAX; mini[s][r] = 0; }

    const _Float16* ehc = eh + (size_t)c * MCODE * DIM;
    const _Float16* elc = el + (size_t)c * MCODE * DIM;
    const float*    d0c = d0 + c * MCODE;

    // ---- sweep 32 n-tiles of 16 codes ----
#pragma unroll 2
    for (int nt = 0; nt < 32; ++nt) {
        const int nbase = nt * 16;
        const int n = nbase + col;
        const _Float16* bh = ehc + (size_t)n * DIM + quad * 8;
        const _Float16* bl = elc + (size_t)n * DIM + quad * 8;
        half8 Bh0 = *(const half8*)(bh);
        half8 Bh1 = *(const half8*)(bh + 32);
        half8 Bl0 = *(const half8*)(bl);
        half8 Bl1 = *(const half8*)(bl + 32);
        float d0v = d0c[n];

#pragma unroll
        for (int s = 0; s < NSUB; ++s) {
            floatx4 acc = {0.f, 0.f, 0.f, 0.f};
            acc = __builtin_amdgcn_mfma_f32_16x16x32_f16(Ahi[s][0], Bh0, acc, 0, 0, 0);
            acc = __builtin_amdgcn_mfma_f32_16x16x32_f16(Ahi[s][1], Bh1, acc, 0, 0, 0);
            acc = __builtin_amdgcn_mfma_f32_16x16x32_f16(Alo[s][0], Bh0, acc, 0, 0, 0);
            acc = __builtin_amdgcn_mfma_f32_16x16x32_f16(Alo[s][1], Bh1, acc, 0, 0, 0);
            acc = __builtin_amdgcn_mfma_f32_16x16x32_f16(Ahi[s][0], Bl0, acc, 0, 0, 0);
            acc = __builtin_amdgcn_mfma_f32_16x16x32_f16(Ahi[s][1], Bl1, acc, 0, 0, 0);
#pragma unroll
            for (int r = 0; r < 4; ++r) {
                float dv = fmaf(-2.f, acc[r], d0v);   // alpha*(e2 - 2 x.e)
                if (dv < minv[s][r]) { minv[s][r] = dv; mini[s][r] = n; }
            }
        }
    }

    // ---- reduce across the 16 col-lanes of each quad (first-min tie-break) ----
#pragma unroll
    for (int off = 1; off < 16; off <<= 1) {
#pragma unroll
        for (int s = 0; s < NSUB; ++s)
#pragma unroll
            for (int r = 0; r < 4; ++r) {
                float ov = __shfl_xor(minv[s][r], off);
                int   oi = __shfl_xor(mini[s][r], off);
                if (ov < minv[s][r] || (ov == minv[s][r] && oi < mini[s][r])) {
                    minv[s][r] = ov; mini[s][r] = oi;
                }
            }
    }
    if (col == 0) {
        // rows for subtile s: token = w*32 + s*16 + quad*4 + r
#pragma unroll
        for (int s = 0; s < NSUB; ++s)
#pragma unroll
            for (int r = 0; r < 4; ++r)
                Is[w * 32 + s * 16 + quad * 4 + r] = mini[s][r];
    }
    __syncthreads();

    // ---- indices + histogram ----
    if (tid < TOK_TILE) {
        int idx = Is[tid];
        atomicAdd(&counts[c * MCODE + idx], 1);
        outIdx[(size_t)(n0tk + tid) * NCB + c] = (float)idx;
    }

    // ---- quantized_st + loss (original fp32 emb for exactness) ----
    float lloss = 0.f;
#pragma unroll
    for (int i = 0; i < 8; ++i) {
        int q = tid + i * 256;
        int tok = q >> 4, d4 = q & 15;
        int idx = Is[tok];
        float mv = mask[(size_t)(n0tk + tok) * NCB + c];
        float4 e4 = *(const float4*)(emb + ((size_t)c * MCODE + idx) * DIM + d4 * 4);
        float4 x4 = *(const float4*)(Xs + tok * XS_STRIDE + d4 * 4);
        float qx = e4.x * mv, qy = e4.y * mv, qz = e4.z * mv, qw = e4.w * mv;
        float4 o;
        o.x = x4.x + (qx - x4.x);
        o.y = x4.y + (qy - x4.y);
        o.z = x4.z + (qz - x4.z);
        o.w = x4.w + (qw - x4.w);
        *(float4*)(outQ + (size_t)(n0tk + tok) * (NCB * DIM) + c * DIM + d4 * 4) = o;
        float dx = x4.x - qx, dy = x4.y - qy, dz = x4.z - qz, dw = x4.w - qw;
        lloss += dx * dx + dy * dy + dz * dz + dw * dw;
    }
#pragma unroll
    for (int off = 32; off > 0; off >>= 1) lloss += __shfl_xor(lloss, off);
    if ((tid & 63) == 0) wls[tid >> 6] = lloss;
    __syncthreads();
    if (tid == 0) {
        float s = wls[0] + wls[1] + wls[2] + wls[3];
        atomicAdd(lossSum, s);
    }
}

__global__ __launch_bounds__(256) void finalize_kernel(const int* __restrict__ counts,
                                                       const float* __restrict__ lossSum,
                                                       float* __restrict__ out) {
    __shared__ float wls[4];
    int tid = threadIdx.x;
    float s = 0.f;
#pragma unroll
    for (int i = 0; i < 8; ++i) {
        int j = tid + i * 256;
        float p = (float)counts[j] * (1.0f / 65536.0f);
        s += p * logf(p + 1e-10f);
    }
#pragma unroll
    for (int off = 32; off > 0; off >>= 1) s += __shfl_xor(s, off);
    if ((tid & 63) == 0) wls[tid >> 6] = s;
    __syncthreads();
    if (tid == 0) {
        float tot = wls[0] + wls[1] + wls[2] + wls[3];
        float L = *lossSum * (1.0f / (float)QST_SIZE);
        out[QST_SIZE + 0] = 0.25f * L;   // commitment_loss
        out[QST_SIZE + 1] = L;           // codebook_loss
        out[QST_SIZE + 2] = expf(-tot);  // perplexity
    }
}

extern "C" void kernel_launch(void* const* d_in, const int* in_sizes, int n_in,
                              void* d_out, int out_size, void* d_ws, size_t ws_size,
                              hipStream_t stream) {
    const float* x    = (const float*)d_in[0];
    const float* emb  = (const float*)d_in[1];
    const float* mask = (const float*)d_in[2];
    float* out = (float*)d_out;

    _Float16* eh   = (_Float16*)((char*)d_ws + WS_EH);
    _Float16* el   = (_Float16*)((char*)d_ws + WS_EL);
    float* d0      = (float*)((char*)d_ws + WS_D0);
    int*   counts  = (int*)((char*)d_ws + WS_CNT);
    float* lossSum = (float*)((char*)d_ws + WS_LOSS);

    prep_kernel<<<dim3(8), dim3(256), 0, stream>>>(emb, eh, el, d0, counts, lossSum);
    vq_main<<<dim3(NTOK / TOK_TILE, NCB), dim3(256), 0, stream>>>(
        x, emb, mask, eh, el, d0, counts, lossSum, out, out + IDX_OFF);
    finalize_kernel<<<dim3(1), dim3(256), 0, stream>>>(counts, lossSum, out);
}

// Round 2
// 248.158 us; speedup vs baseline: 1.0988x; 1.0988x over previous
//
#include <hip/hip_runtime.h>
#include <math.h>
#include <float.h>

// Problem constants
#define NTOK 65536
#define NCB  4
#define MCODE 512
#define DIM  64

#define QST_SIZE (NTOK * NCB * DIM)        // 16777216
#define IDX_OFF  (QST_SIZE + 3)            // 16777219

// Tiles
#define TOK_TILE  256                      // tokens per block (64 per wave, NSUB=4)
#define NSUB      4

// ws layout (bytes):
//   eh  f16[2048*64]  @ 0        (262144)   hi half of 512*e
//   el  f16[2048*64]  @ 262144   (262144)   lo half
//   d0  f32[2048]     @ 524288   (8192)     512 * sum(e^2)
//   counts int[2048]  @ 532480   (8192)
//   lossSum f32       @ 540672
#define WS_EH 0
#define WS_EL 262144
#define WS_D0 524288
#define WS_CNT 532480
#define WS_LOSS 540672

typedef _Float16 half8 __attribute__((ext_vector_type(8)));
typedef float floatx4 __attribute__((ext_vector_type(4)));

// ---- prep: f16 hi/lo split of 512*e, d0 = 512*|e|^2, zero counts/loss ----
__global__ __launch_bounds__(256) void prep_kernel(const float* __restrict__ emb,
                                                   _Float16* __restrict__ eh,
                                                   _Float16* __restrict__ el,
                                                   float* __restrict__ d0,
                                                   int* __restrict__ counts,
                                                   float* __restrict__ lossSum) {
    int row = blockIdx.x * 256 + threadIdx.x;   // 0..2047  (grid=8)
    if (row >= NCB * MCODE) return;
    const float* src = emb + (size_t)row * DIM;
    _Float16* ph = eh + (size_t)row * DIM;
    _Float16* pl = el + (size_t)row * DIM;
    float s = 0.f;
#pragma unroll
    for (int j = 0; j < DIM / 8; ++j) {
        half8 h, l;
#pragma unroll
        for (int t = 0; t < 8; ++t) {
            float e = src[j * 8 + t];
            s += e * e;
            float f = e * 512.0f;
            _Float16 hi = (_Float16)f;
            float r = f - (float)hi;
            h[t] = hi;
            l[t] = (_Float16)r;
        }
        *(half8*)(ph + j * 8) = h;
        *(half8*)(pl + j * 8) = l;
    }
    d0[row] = 512.0f * s;
    counts[row] = 0;
    if (row == 0) *lossSum = 0.f;
}

// ---- main: MFMA distances + argmin + epilogue ----
// block = 256 threads = 4 waves; each wave owns 64 tokens (4 subtiles of 16).
// No X LDS tile: A-fragments built straight from global (coalesced 128B-line
// pattern); epilogue re-reads x from global. LDS ~1KB -> occupancy VGPR-bound.
__global__ __launch_bounds__(256) void vq_main(const float* __restrict__ x,
                                               const float* __restrict__ emb,
                                               const float* __restrict__ mask,
                                               const _Float16* __restrict__ eh,
                                               const _Float16* __restrict__ el,
                                               const float* __restrict__ d0,
                                               int* __restrict__ counts,
                                               float* __restrict__ lossSum,
                                               float* __restrict__ outQ,
                                               float* __restrict__ outIdx) {
    __shared__ int   Is[TOK_TILE];
    __shared__ float wls[4];

    const int tid  = threadIdx.x;
    const int c    = blockIdx.y;
    const int n0tk = blockIdx.x * TOK_TILE;
    const int lane = tid & 63;
    const int w    = tid >> 6;            // wave id 0..3
    const int col  = lane & 15;           // MFMA col (code within tile) / row m in A
    const int quad = lane >> 4;           // 0..3

    // ---- build persistent A fragments (hi/lo) for this wave's 64 tokens ----
    // subtile s: token = w*64 + s*16 + col ; kstep ks: k = ks*32 + quad*8 + j
    // One load instruction touches 16 tokens x one 128B-line-chunk: coalesced.
    half8 Ahi[NSUB][2], Alo[NSUB][2];
    {
        const float* xw = x + (size_t)(n0tk + w * 64 + col) * (NCB * DIM) + c * DIM + quad * 8;
#pragma unroll
        for (int s = 0; s < NSUB; ++s) {
#pragma unroll
            for (int ks = 0; ks < 2; ++ks) {
                const float* p = xw + (size_t)(s * 16) * (NCB * DIM) + ks * 32;
                float fv[8];
                *(float4*)(fv)     = *(const float4*)(p);
                *(float4*)(fv + 4) = *(const float4*)(p + 4);
                half8 h, l;
#pragma unroll
                for (int t = 0; t < 8; ++t) {
                    float f = fv[t];
                    _Float16 hi = (_Float16)f;
                    float r = f - (float)hi;
                    h[t] = hi;
                    l[t] = (_Float16)r;
                }
                Ahi[s][ks] = h;
                Alo[s][ks] = l;
            }
        }
    }

    float minv[NSUB][4];
    int   mini[NSUB][4];
#pragma unroll
    for (int s = 0; s < NSUB; ++s)
#pragma unroll
        for (int r = 0; r < 4; ++r) { minv[s][r] = FLT_MAX; mini[s][r] = 0; }

    const _Float16* ehc = eh + (size_t)c * MCODE * DIM;
    const _Float16* elc = el + (size_t)c * MCODE * DIM;
    const float*    d0c = d0 + c * MCODE;

    // ---- sweep 32 n-tiles of 16 codes, software-pipelined B loads ----
    half8 cBh0, cBh1, cBl0, cBl1;
    float cd0;
    {
        const _Float16* ph = ehc + (size_t)col * DIM + quad * 8;
        const _Float16* pl = elc + (size_t)col * DIM + quad * 8;
        cBh0 = *(const half8*)(ph);
        cBh1 = *(const half8*)(ph + 32);
        cBl0 = *(const half8*)(pl);
        cBl1 = *(const half8*)(pl + 32);
        cd0  = d0c[col];
    }

#pragma unroll 2
    for (int nt = 0; nt < 32; ++nt) {
        // prefetch nt+1 (wraps to 0 on the last iter; harmless reload)
        const int n2 = (((nt + 1) & 31) * 16) + col;
        const _Float16* ph = ehc + (size_t)n2 * DIM + quad * 8;
        const _Float16* pl = elc + (size_t)n2 * DIM + quad * 8;
        half8 nBh0 = *(const half8*)(ph);
        half8 nBh1 = *(const half8*)(ph + 32);
        half8 nBl0 = *(const half8*)(pl);
        half8 nBl1 = *(const half8*)(pl + 32);
        float nd0  = d0c[n2];

        const int n = nt * 16 + col;
#pragma unroll
        for (int s = 0; s < NSUB; ++s) {
            // two independent 3-deep chains instead of one 6-deep chain
            floatx4 a0 = {0.f, 0.f, 0.f, 0.f};
            floatx4 a1 = {0.f, 0.f, 0.f, 0.f};
            a0 = __builtin_amdgcn_mfma_f32_16x16x32_f16(Ahi[s][0], cBh0, a0, 0, 0, 0);
            a1 = __builtin_amdgcn_mfma_f32_16x16x32_f16(Ahi[s][1], cBh1, a1, 0, 0, 0);
            a0 = __builtin_amdgcn_mfma_f32_16x16x32_f16(Alo[s][0], cBh0, a0, 0, 0, 0);
            a1 = __builtin_amdgcn_mfma_f32_16x16x32_f16(Alo[s][1], cBh1, a1, 0, 0, 0);
            a0 = __builtin_amdgcn_mfma_f32_16x16x32_f16(Ahi[s][0], cBl0, a0, 0, 0, 0);
            a1 = __builtin_amdgcn_mfma_f32_16x16x32_f16(Ahi[s][1], cBl1, a1, 0, 0, 0);
#pragma unroll
            for (int r = 0; r < 4; ++r) {
                float dv = fmaf(-2.f, a0[r] + a1[r], cd0);   // alpha*(e2 - 2 x.e)
                if (dv < minv[s][r]) { minv[s][r] = dv; mini[s][r] = n; }
            }
        }

        cBh0 = nBh0; cBh1 = nBh1; cBl0 = nBl0; cBl1 = nBl1; cd0 = nd0;
    }

    // ---- reduce across the 16 col-lanes of each quad (first-min tie-break) ----
#pragma unroll
    for (int off = 1; off < 16; off <<= 1) {
#pragma unroll
        for (int s = 0; s < NSUB; ++s)
#pragma unroll
            for (int r = 0; r < 4; ++r) {
                float ov = __shfl_xor(minv[s][r], off);
                int   oi = __shfl_xor(mini[s][r], off);
                if (ov < minv[s][r] || (ov == minv[s][r] && oi < mini[s][r])) {
                    minv[s][r] = ov; mini[s][r] = oi;
                }
            }
    }
    if (col == 0) {
        // rows for subtile s: token = w*64 + s*16 + quad*4 + r
#pragma unroll
        for (int s = 0; s < NSUB; ++s)
#pragma unroll
            for (int r = 0; r < 4; ++r)
                Is[w * 64 + s * 16 + quad * 4 + r] = mini[s][r];
    }
    __syncthreads();

    // ---- indices + histogram ----
    {
        int idx = Is[tid];
        atomicAdd(&counts[c * MCODE + idx], 1);
        outIdx[(size_t)(n0tk + tid) * NCB + c] = (float)idx;
    }

    // ---- quantized_st + loss (original fp32 emb + fp32 x for exactness) ----
    float lloss = 0.f;
#pragma unroll
    for (int i = 0; i < 16; ++i) {
        int q = tid + i * 256;
        int tok = q >> 4, d4 = q & 15;
        int idx = Is[tok];
        float mv = mask[(size_t)(n0tk + tok) * NCB + c];
        float4 e4 = *(const float4*)(emb + ((size_t)c * MCODE + idx) * DIM + d4 * 4);
        float4 x4 = *(const float4*)(x + (size_t)(n0tk + tok) * (NCB * DIM) + c * DIM + d4 * 4);
        float qx = e4.x * mv, qy = e4.y * mv, qz = e4.z * mv, qw = e4.w * mv;
        float4 o;
        o.x = x4.x + (qx - x4.x);
        o.y = x4.y + (qy - x4.y);
        o.z = x4.z + (qz - x4.z);
        o.w = x4.w + (qw - x4.w);
        *(float4*)(outQ + (size_t)(n0tk + tok) * (NCB * DIM) + c * DIM + d4 * 4) = o;
        float dx = x4.x - qx, dy = x4.y - qy, dz = x4.z - qz, dw = x4.w - qw;
        lloss += dx * dx + dy * dy + dz * dz + dw * dw;
    }
#pragma unroll
    for (int off = 32; off > 0; off >>= 1) lloss += __shfl_xor(lloss, off);
    if ((tid & 63) == 0) wls[tid >> 6] = lloss;
    __syncthreads();
    if (tid == 0) {
        float s = wls[0] + wls[1] + wls[2] + wls[3];
        atomicAdd(lossSum, s);
    }
}

__global__ __launch_bounds__(256) void finalize_kernel(const int* __restrict__ counts,
                                                       const float* __restrict__ lossSum,
                                                       float* __restrict__ out) {
    __shared__ float wls[4];
    int tid = threadIdx.x;
    float s = 0.f;
#pragma unroll
    for (int i = 0; i < 8; ++i) {
        int j = tid + i * 256;
        float p = (float)counts[j] * (1.0f / 65536.0f);
        s += p * logf(p + 1e-10f);
    }
#pragma unroll
    for (int off = 32; off > 0; off >>= 1) s += __shfl_xor(s, off);
    if ((tid & 63) == 0) wls[tid >> 6] = s;
    __syncthreads();
    if (tid == 0) {
        float tot = wls[0] + wls[1] + wls[2] + wls[3];
        float L = *lossSum * (1.0f / (float)QST_SIZE);
        out[QST_SIZE + 0] = 0.25f * L;   // commitment_loss
        out[QST_SIZE + 1] = L;           // codebook_loss
        out[QST_SIZE + 2] = expf(-tot);  // perplexity
    }
}

extern "C" void kernel_launch(void* const* d_in, const int* in_sizes, int n_in,
                              void* d_out, int out_size, void* d_ws, size_t ws_size,
                              hipStream_t stream) {
    const float* x    = (const float*)d_in[0];
    const float* emb  = (const float*)d_in[1];
    const float* mask = (const float*)d_in[2];
    float* out = (float*)d_out;

    _Float16* eh   = (_Float16*)((char*)d_ws + WS_EH);
    _Float16* el   = (_Float16*)((char*)d_ws + WS_EL);
    float* d0      = (float*)((char*)d_ws + WS_D0);
    int*   counts  = (int*)((char*)d_ws + WS_CNT);
    float* lossSum = (float*)((char*)d_ws + WS_LOSS);

    prep_kernel<<<dim3(8), dim3(256), 0, stream>>>(emb, eh, el, d0, counts, lossSum);
    vq_main<<<dim3(NTOK / TOK_TILE, NCB), dim3(256), 0, stream>>>(
        x, emb, mask, eh, el, d0, counts, lossSum, out, out + IDX_OFF);
    finalize_kernel<<<dim3(1), dim3(256), 0, stream>>>(counts, lossSum, out);
}

// Round 3
// 211.350 us; speedup vs baseline: 1.2902x; 1.1742x over previous
//
#include <hip/hip_runtime.h>
#include <math.h>
#include <float.h>

// Problem constants
#define NTOK 65536
#define NCB  4
#define MCODE 512
#define DIM  64

#define QST_SIZE (NTOK * NCB * DIM)        // 16777216
#define IDX_OFF  (QST_SIZE + 3)            // 16777219

// Tiles: 4 waves/block, each wave owns 32 tokens (one 32-wide MFMA column tile)
#define TOK_TILE  128

// ws layout (bytes):
//   ehf f16[4*16*4*512] @ 0        (262144)  hi half of 512*e, MFMA-fragment order
//   elf f16[4*16*4*512] @ 262144   (262144)  lo half, fragment order
//   d0p f32[2048]       @ 524288   (8192)    -256 * sum(e^2)  (acc C-init)
//   counts int[2048]    @ 532480   (8192)
//   lossSum f32         @ 540672
#define WS_EH 0
#define WS_EL 262144
#define WS_D0 524288
#define WS_CNT 532480
#define WS_LOSS 540672

typedef _Float16 half8 __attribute__((ext_vector_type(8)));
typedef float floatx16 __attribute__((ext_vector_type(16)));

// ---- prep: fragment-order f16 hi/lo split of 512*e, d0p = -256*|e|^2 ----
// Fragment layout for A-operand of 32x32x16: for (c, nt, ch):
//   512 f16 block; lane = h*32 + row5 holds rows (nt*32+row5), k = ch*16 + h*8 + t
__global__ __launch_bounds__(256) void prep_kernel(const float* __restrict__ emb,
                                                   _Float16* __restrict__ ehf,
                                                   _Float16* __restrict__ elf,
                                                   float* __restrict__ d0p,
                                                   int* __restrict__ counts,
                                                   float* __restrict__ lossSum) {
    int row = blockIdx.x * 256 + threadIdx.x;   // 0..2047  (grid=8)
    if (row >= NCB * MCODE) return;
    const int c   = row >> 9;
    const int n   = row & 511;
    const int nt  = n >> 5;
    const int r5  = n & 31;
    const float* src = emb + (size_t)row * DIM;

    float s = 0.f;
#pragma unroll
    for (int ch = 0; ch < 4; ++ch) {
#pragma unroll
        for (int h = 0; h < 2; ++h) {
            half8 hv, lv;
#pragma unroll
            for (int t = 0; t < 8; ++t) {
                float e = src[ch * 16 + h * 8 + t];
                s += e * e;
                float f = e * 512.0f;
                _Float16 hi = (_Float16)f;
                float r = f - (float)hi;
                hv[t] = hi;
                lv[t] = (_Float16)r;
            }
            size_t off = ((size_t)((c * 16 + nt) * 4 + ch)) * 512 + (h * 32 + r5) * 8;
            *(half8*)(ehf + off) = hv;
            *(half8*)(elf + off) = lv;
        }
    }
    d0p[row] = -256.0f * s;
    counts[row] = 0;
    if (row == 0) *lossSum = 0.f;
}

// ---- main: 32x32x16 MFMA distances + per-lane argmin + epilogue ----
// A = codes (streamed from fragment-order ws), B = tokens (persistent, 32 VGPR).
// acc col = token (lane&31) -> each lane owns ONE token; 16 acc regs = 16 codes.
// d0 folded into acc C-init => maximize m = sum(x*512e) - 256*sum(e^2).
__global__ __launch_bounds__(256) void vq_main(const float* __restrict__ x,
                                               const float* __restrict__ emb,
                                               const float* __restrict__ mask,
                                               const _Float16* __restrict__ ehf,
                                               const _Float16* __restrict__ elf,
                                               const float* __restrict__ d0p,
                                               int* __restrict__ counts,
                                               float* __restrict__ lossSum,
                                               float* __restrict__ outQ,
                                               float* __restrict__ outIdx) {
    __shared__ int   Is[TOK_TILE];
    __shared__ float wls[4];

    const int tid  = threadIdx.x;
    const int c    = blockIdx.y;
    const int n0tk = blockIdx.x * TOK_TILE;
    const int lane = tid & 63;
    const int w    = tid >> 6;            // wave id 0..3
    const int l31  = lane & 31;           // token within wave tile / acc column
    const int hi   = lane >> 5;           // k-half for A/B, row-half for C
    const int hi4  = hi * 4;

    // ---- persistent B fragments (x hi/lo) for this lane's token ----
    // B col = lane&31 = token; k = ch*16 + hi*8 + t
    half8 Bh[4], Bl[4];
    {
        const float* xr = x + (size_t)(n0tk + w * 32 + l31) * (NCB * DIM) + c * DIM + hi * 8;
#pragma unroll
        for (int ch = 0; ch < 4; ++ch) {
            float fv[8];
            *(float4*)(fv)     = *(const float4*)(xr + ch * 16);
            *(float4*)(fv + 4) = *(const float4*)(xr + ch * 16 + 4);
            half8 h8, l8;
#pragma unroll
            for (int t = 0; t < 8; ++t) {
                float f = fv[t];
                _Float16 hh = (_Float16)f;
                h8[t] = hh;
                l8[t] = (_Float16)(f - (float)hh);
            }
            Bh[ch] = h8;
            Bl[ch] = l8;
        }
    }

    const _Float16* Ah_base = ehf + (size_t)c * (16 * 4 * 512) + (size_t)lane * 8;
    const _Float16* Al_base = elf + (size_t)c * (16 * 4 * 512) + (size_t)lane * 8;
    const float*    d0c     = d0p + c * MCODE;

    float maxv = -FLT_MAX;
    int   maxn = 0;

    // ---- sweep 16 n-tiles of 32 codes ----
    for (int nt = 0; nt < 16; ++nt) {
        // A fragment loads (hi/lo, 4 k-chunks) — fully coalesced 16B/lane
        const _Float16* pah = Ah_base + (size_t)nt * 2048;
        const _Float16* pal = Al_base + (size_t)nt * 2048;
        half8 Ah0 = *(const half8*)(pah);
        half8 Ah1 = *(const half8*)(pah + 512);
        half8 Ah2 = *(const half8*)(pah + 1024);
        half8 Ah3 = *(const half8*)(pah + 1536);
        half8 Al0 = *(const half8*)(pal);
        half8 Al1 = *(const half8*)(pal + 512);
        half8 Al2 = *(const half8*)(pal + 1024);
        half8 Al3 = *(const half8*)(pal + 1536);

        // acc C-init = -256*|e|^2 per code row (broadcast float4 loads)
        const float* dpt = d0c + nt * 32 + hi4;
        float4 d40 = *(const float4*)(dpt);
        float4 d41 = *(const float4*)(dpt + 8);
        float4 d42 = *(const float4*)(dpt + 16);
        float4 d43 = *(const float4*)(dpt + 24);
        floatx16 acc;
        acc[0]  = d40.x; acc[1]  = d40.y; acc[2]  = d40.z; acc[3]  = d40.w;
        acc[4]  = d41.x; acc[5]  = d41.y; acc[6]  = d41.z; acc[7]  = d41.w;
        acc[8]  = d42.x; acc[9]  = d42.y; acc[10] = d42.z; acc[11] = d42.w;
        acc[12] = d43.x; acc[13] = d43.y; acc[14] = d43.z; acc[15] = d43.w;

        // 12-MFMA chain: (Ah+Al)(Bh+Bl) ≈ AhBh + AlBh + AhBl per k-chunk
        acc = __builtin_amdgcn_mfma_f32_32x32x16_f16(Ah0, Bh[0], acc, 0, 0, 0);
        acc = __builtin_amdgcn_mfma_f32_32x32x16_f16(Al0, Bh[0], acc, 0, 0, 0);
        acc = __builtin_amdgcn_mfma_f32_32x32x16_f16(Ah0, Bl[0], acc, 0, 0, 0);
        acc = __builtin_amdgcn_mfma_f32_32x32x16_f16(Ah1, Bh[1], acc, 0, 0, 0);
        acc = __builtin_amdgcn_mfma_f32_32x32x16_f16(Al1, Bh[1], acc, 0, 0, 0);
        acc = __builtin_amdgcn_mfma_f32_32x32x16_f16(Ah1, Bl[1], acc, 0, 0, 0);
        acc = __builtin_amdgcn_mfma_f32_32x32x16_f16(Ah2, Bh[2], acc, 0, 0, 0);
        acc = __builtin_amdgcn_mfma_f32_32x32x16_f16(Al2, Bh[2], acc, 0, 0, 0);
        acc = __builtin_amdgcn_mfma_f32_32x32x16_f16(Ah2, Bl[2], acc, 0, 0, 0);
        acc = __builtin_amdgcn_mfma_f32_32x32x16_f16(Ah3, Bh[3], acc, 0, 0, 0);
        acc = __builtin_amdgcn_mfma_f32_32x32x16_f16(Al3, Bh[3], acc, 0, 0, 0);
        acc = __builtin_amdgcn_mfma_f32_32x32x16_f16(Ah3, Bl[3], acc, 0, 0, 0);

        // per-lane argmin update over this lane's 16 code rows
        // row(r) = (r&3) + 8*(r>>2) + hi4 + nt*32 — increasing in (nt, r):
        // strict '>' keeps first (lowest index) maximum => first-min of distance
        const int nbase = nt * 32 + hi4;
#pragma unroll
        for (int r = 0; r < 16; ++r) {
            float m = acc[r];
            int   n = nbase + ((r & 3) + 8 * (r >> 2));
            if (m > maxv) { maxv = m; maxn = n; }
        }
    }

    // ---- merge the two row-halves (lane <-> lane+32) ----
    {
        float ov = __shfl_xor(maxv, 32);
        int   on = __shfl_xor(maxn, 32);
        if (ov > maxv || (ov == maxv && on < maxn)) { maxv = ov; maxn = on; }
    }

    if (hi == 0) {
        Is[w * 32 + l31] = maxn;
        atomicAdd(&counts[c * MCODE + maxn], 1);
        outIdx[(size_t)(n0tk + w * 32 + l31) * NCB + c] = (float)maxn;
    }
    __syncthreads();

    // ---- quantized_st + loss (original fp32 emb + fp32 x for exactness) ----
    float lloss = 0.f;
#pragma unroll
    for (int i = 0; i < 8; ++i) {
        int q = tid + i * 256;
        int tok = q >> 4, d4 = q & 15;
        int idx = Is[tok];
        float mv = mask[(size_t)(n0tk + tok) * NCB + c];
        float4 e4 = *(const float4*)(emb + ((size_t)c * MCODE + idx) * DIM + d4 * 4);
        float4 x4 = *(const float4*)(x + (size_t)(n0tk + tok) * (NCB * DIM) + c * DIM + d4 * 4);
        float qx = e4.x * mv, qy = e4.y * mv, qz = e4.z * mv, qw = e4.w * mv;
        float4 o;
        o.x = x4.x + (qx - x4.x);
        o.y = x4.y + (qy - x4.y);
        o.z = x4.z + (qz - x4.z);
        o.w = x4.w + (qw - x4.w);
        *(float4*)(outQ + (size_t)(n0tk + tok) * (NCB * DIM) + c * DIM + d4 * 4) = o;
        float dx = x4.x - qx, dy = x4.y - qy, dz = x4.z - qz, dw = x4.w - qw;
        lloss += dx * dx + dy * dy + dz * dz + dw * dw;
    }
#pragma unroll
    for (int off = 32; off > 0; off >>= 1) lloss += __shfl_xor(lloss, off);
    if ((tid & 63) == 0) wls[tid >> 6] = lloss;
    __syncthreads();
    if (tid == 0) {
        float s = wls[0] + wls[1] + wls[2] + wls[3];
        atomicAdd(lossSum, s);
    }
}

__global__ __launch_bounds__(256) void finalize_kernel(const int* __restrict__ counts,
                                                       const float* __restrict__ lossSum,
                                                       float* __restrict__ out) {
    __shared__ float wls[4];
    int tid = threadIdx.x;
    float s = 0.f;
#pragma unroll
    for (int i = 0; i < 8; ++i) {
        int j = tid + i * 256;
        float p = (float)counts[j] * (1.0f / 65536.0f);
        s += p * logf(p + 1e-10f);
    }
#pragma unroll
    for (int off = 32; off > 0; off >>= 1) s += __shfl_xor(s, off);
    if ((tid & 63) == 0) wls[tid >> 6] = s;
    __syncthreads();
    if (tid == 0) {
        float tot = wls[0] + wls[1] + wls[2] + wls[3];
        float L = *lossSum * (1.0f / (float)QST_SIZE);
        out[QST_SIZE + 0] = 0.25f * L;   // commitment_loss
        out[QST_SIZE + 1] = L;           // codebook_loss
        out[QST_SIZE + 2] = expf(-tot);  // perplexity
    }
}

extern "C" void kernel_launch(void* const* d_in, const int* in_sizes, int n_in,
                              void* d_out, int out_size, void* d_ws, size_t ws_size,
                              hipStream_t stream) {
    const float* x    = (const float*)d_in[0];
    const float* emb  = (const float*)d_in[1];
    const float* mask = (const float*)d_in[2];
    float* out = (float*)d_out;

    _Float16* ehf  = (_Float16*)((char*)d_ws + WS_EH);
    _Float16* elf  = (_Float16*)((char*)d_ws + WS_EL);
    float* d0p     = (float*)((char*)d_ws + WS_D0);
    int*   counts  = (int*)((char*)d_ws + WS_CNT);
    float* lossSum = (float*)((char*)d_ws + WS_LOSS);

    prep_kernel<<<dim3(8), dim3(256), 0, stream>>>(emb, ehf, elf, d0p, counts, lossSum);
    vq_main<<<dim3(NTOK / TOK_TILE, NCB), dim3(256), 0, stream>>>(
        x, emb, mask, ehf, elf, d0p, counts, lossSum, out, out + IDX_OFF);
    finalize_kernel<<<dim3(1), dim3(256), 0, stream>>>(counts, lossSum, out);
}

// Round 5
// 202.581 us; speedup vs baseline: 1.3461x; 1.0433x over previous
//
#include <hip/hip_runtime.h>
#include <math.h>
#include <float.h>

// Problem constants
#define NTOK 65536
#define NCB  4
#define MCODE 512
#define DIM  64

#define QST_SIZE (NTOK * NCB * DIM)        // 16777216
#define IDX_OFF  (QST_SIZE + 3)            // 16777219

// Tiles: 4 waves/block, each wave owns 32 tokens (one 32-wide MFMA column tile)
#define TOK_TILE  128

// ws layout (bytes):
//   ehf f16[4*16*4*512] @ 0        (262144)  hi half of 512*e, MFMA-fragment order
//   elf f16[4*16*4*512] @ 262144   (262144)  lo half, fragment order
//   d0p f32[2048]       @ 524288   (8192)    -256 * sum(e^2)  (acc C-init)
//   counts int[2048]    @ 532480   (8192)
//   lossSum f32         @ 540672
#define WS_EH 0
#define WS_EL 262144
#define WS_D0 524288
#define WS_CNT 532480
#define WS_LOSS 540672

typedef _Float16 half8 __attribute__((ext_vector_type(8)));
typedef float floatx16 __attribute__((ext_vector_type(16)));

// ---- prep: fragment-order f16 hi/lo split of 512*e, d0p = -256*|e|^2 ----
// Fragment layout for A-operand of 32x32x16: for (c, nt, ch):
//   512 f16 block; lane = h*32 + row5 holds rows (nt*32+row5), k = ch*16 + h*8 + t
__global__ __launch_bounds__(256) void prep_kernel(const float* __restrict__ emb,
                                                   _Float16* __restrict__ ehf,
                                                   _Float16* __restrict__ elf,
                                                   float* __restrict__ d0p,
                                                   int* __restrict__ counts,
                                                   float* __restrict__ lossSum) {
    int row = blockIdx.x * 256 + threadIdx.x;   // 0..2047  (grid=8)
    if (row >= NCB * MCODE) return;
    const int c   = row >> 9;
    const int n   = row & 511;
    const int nt  = n >> 5;
    const int r5  = n & 31;
    const float* src = emb + (size_t)row * DIM;

    float s = 0.f;
#pragma unroll
    for (int ch = 0; ch < 4; ++ch) {
#pragma unroll
        for (int h = 0; h < 2; ++h) {
            half8 hv, lv;
#pragma unroll
            for (int t = 0; t < 8; ++t) {
                float e = src[ch * 16 + h * 8 + t];
                s += e * e;
                float f = e * 512.0f;
                _Float16 hi = (_Float16)f;
                float r = f - (float)hi;
                hv[t] = hi;
                lv[t] = (_Float16)r;
            }
            size_t off = ((size_t)((c * 16 + nt) * 4 + ch)) * 512 + (h * 32 + r5) * 8;
            *(half8*)(ehf + off) = hv;
            *(half8*)(elf + off) = lv;
        }
    }
    d0p[row] = -256.0f * s;
    counts[row] = 0;
    if (row == 0) *lossSum = 0.f;
}

// ---- main: 32x32x16 MFMA + per-lane argmin; A staged through dbuf LDS ----
// A = codes (block-shared LDS stream), B = tokens (persistent, 32 VGPR).
// Per nt: prefetch chunk nt+1 global->regs (top), compute nt from LDS,
// ds_write regs->LDS[buf^1] (bottom), one barrier. 4x A-traffic reduction.
__global__ __launch_bounds__(256) void vq_main(const float* __restrict__ x,
                                               const float* __restrict__ emb,
                                               const float* __restrict__ mask,
                                               const _Float16* __restrict__ ehf,
                                               const _Float16* __restrict__ elf,
                                               const float* __restrict__ d0p,
                                               int* __restrict__ counts,
                                               float* __restrict__ lossSum,
                                               float* __restrict__ outQ,
                                               float* __restrict__ outIdx) {
    __shared__ __align__(16) _Float16 As[2][4096];   // [buf][eh 2048 | el 2048] = 16 KB
    __shared__ __align__(16) float d0s[MCODE];       // 2 KB
    __shared__ int   Is[TOK_TILE];
    __shared__ float wls[4];

    const int tid  = threadIdx.x;
    const int c    = blockIdx.y;
    const int n0tk = blockIdx.x * TOK_TILE;
    const int lane = tid & 63;
    const int w    = tid >> 6;            // wave id 0..3
    const int l31  = lane & 31;           // token within wave tile / acc column
    const int hi   = lane >> 5;           // k-half for A/B, row-half for C
    const int hi4  = hi * 4;

    const _Float16* gEh = ehf + (size_t)c * (16 * 4 * 512);
    const _Float16* gEl = elf + (size_t)c * (16 * 4 * 512);

    // ---- stage chunk 0 + d0 into LDS (loads first, for overlap with B-build) ----
    float4 sh = *(const float4*)(gEh + tid * 8);
    float4 sl = *(const float4*)(gEl + tid * 8);
    float4 dstage;
    if (tid < 128) dstage = *(const float4*)(d0p + c * MCODE + tid * 4);

    // ---- persistent B fragments (x hi/lo) for this lane's token ----
    // B col = lane&31 = token; k = ch*16 + hi*8 + t
    half8 Bh[4], Bl[4];
    {
        const float* xr = x + (size_t)(n0tk + w * 32 + l31) * (NCB * DIM) + c * DIM + hi * 8;
#pragma unroll
        for (int ch = 0; ch < 4; ++ch) {
            float fv[8];
            *(float4*)(fv)     = *(const float4*)(xr + ch * 16);
            *(float4*)(fv + 4) = *(const float4*)(xr + ch * 16 + 4);
            half8 h8, l8;
#pragma unroll
            for (int t = 0; t < 8; ++t) {
                float f = fv[t];
                _Float16 hh = (_Float16)f;
                h8[t] = hh;
                l8[t] = (_Float16)(f - (float)hh);
            }
            Bh[ch] = h8;
            Bl[ch] = l8;
        }
    }

    *(float4*)((char*)&As[0][0]    + tid * 16) = sh;
    *(float4*)((char*)&As[0][2048] + tid * 16) = sl;
    if (tid < 128) *(float4*)(&d0s[tid * 4]) = dstage;
    __syncthreads();

    float maxv = -FLT_MAX;
    int   maxn = 0;

    // ---- sweep 16 n-tiles of 32 codes, dbuf LDS + 1-ahead prefetch ----
    for (int nt = 0; nt < 16; ++nt) {
        const int p = nt & 1;

        // prefetch next chunk to regs (latency hides under MFMA+argmin below)
        float4 nh, nl;
        if (nt < 15) {
            nh = *(const float4*)(gEh + (nt + 1) * 2048 + tid * 8);
            nl = *(const float4*)(gEl + (nt + 1) * 2048 + tid * 8);
        }

        // A fragment reads from LDS (stride-1 b128, standard pattern)
        const _Float16* ah = &As[p][0] + lane * 8;
        const _Float16* al = &As[p][2048] + lane * 8;
        half8 Ah0 = *(const half8*)(ah);
        half8 Ah1 = *(const half8*)(ah + 512);
        half8 Ah2 = *(const half8*)(ah + 1024);
        half8 Ah3 = *(const half8*)(ah + 1536);
        half8 Al0 = *(const half8*)(al);
        half8 Al1 = *(const half8*)(al + 512);
        half8 Al2 = *(const half8*)(al + 1024);
        half8 Al3 = *(const half8*)(al + 1536);

        // acc C-init = -256*|e|^2 per code row (LDS broadcast reads)
        const float* dpt = &d0s[nt * 32 + hi4];
        float4 d40 = *(const float4*)(dpt);
        float4 d41 = *(const float4*)(dpt + 8);
        float4 d42 = *(const float4*)(dpt + 16);
        float4 d43 = *(const float4*)(dpt + 24);
        floatx16 acc;
        acc[0]  = d40.x; acc[1]  = d40.y; acc[2]  = d40.z; acc[3]  = d40.w;
        acc[4]  = d41.x; acc[5]  = d41.y; acc[6]  = d41.z; acc[7]  = d41.w;
        acc[8]  = d42.x; acc[9]  = d42.y; acc[10] = d42.z; acc[11] = d42.w;
        acc[12] = d43.x; acc[13] = d43.y; acc[14] = d43.z; acc[15] = d43.w;

        // 12-MFMA chain: (Ah+Al)(Bh+Bl) ≈ AhBh + AlBh + AhBl per k-chunk
        acc = __builtin_amdgcn_mfma_f32_32x32x16_f16(Ah0, Bh[0], acc, 0, 0, 0);
        acc = __builtin_amdgcn_mfma_f32_32x32x16_f16(Al0, Bh[0], acc, 0, 0, 0);
        acc = __builtin_amdgcn_mfma_f32_32x32x16_f16(Ah0, Bl[0], acc, 0, 0, 0);
        acc = __builtin_amdgcn_mfma_f32_32x32x16_f16(Ah1, Bh[1], acc, 0, 0, 0);
        acc = __builtin_amdgcn_mfma_f32_32x32x16_f16(Al1, Bh[1], acc, 0, 0, 0);
        acc = __builtin_amdgcn_mfma_f32_32x32x16_f16(Ah1, Bl[1], acc, 0, 0, 0);
        acc = __builtin_amdgcn_mfma_f32_32x32x16_f16(Ah2, Bh[2], acc, 0, 0, 0);
        acc = __builtin_amdgcn_mfma_f32_32x32x16_f16(Al2, Bh[2], acc, 0, 0, 0);
        acc = __builtin_amdgcn_mfma_f32_32x32x16_f16(Ah2, Bl[2], acc, 0, 0, 0);
        acc = __builtin_amdgcn_mfma_f32_32x32x16_f16(Ah3, Bh[3], acc, 0, 0, 0);
        acc = __builtin_amdgcn_mfma_f32_32x32x16_f16(Al3, Bh[3], acc, 0, 0, 0);
        acc = __builtin_amdgcn_mfma_f32_32x32x16_f16(Ah3, Bl[3], acc, 0, 0, 0);

        // per-lane argmin update over this lane's 16 code rows
        // row(r) = (r&3) + 8*(r>>2) + hi4 + nt*32 — increasing in (nt, r):
        // strict '>' keeps first (lowest index) maximum => first-min of distance
        const int nbase = nt * 32 + hi4;
#pragma unroll
        for (int r = 0; r < 16; ++r) {
            float m = acc[r];
            int   n = nbase + ((r & 3) + 8 * (r >> 2));
            if (m > maxv) { maxv = m; maxn = n; }
        }

        // write prefetched chunk into the other buffer (forces vmcnt wait here,
        // after compute), then one barrier ends the iteration
        if (nt < 15) {
            *(float4*)((char*)&As[p ^ 1][0]    + tid * 16) = nh;
            *(float4*)((char*)&As[p ^ 1][2048] + tid * 16) = nl;
        }
        __syncthreads();
    }

    // ---- merge the two row-halves (lane <-> lane+32) ----
    {
        float ov = __shfl_xor(maxv, 32);
        int   on = __shfl_xor(maxn, 32);
        if (ov > maxv || (ov == maxv && on < maxn)) { maxv = ov; maxn = on; }
    }

    if (hi == 0) {
        Is[w * 32 + l31] = maxn;
        atomicAdd(&counts[c * MCODE + maxn], 1);
        outIdx[(size_t)(n0tk + w * 32 + l31) * NCB + c] = (float)maxn;
    }
    __syncthreads();

    // ---- quantized_st + loss (original fp32 emb + fp32 x for exactness) ----
    float lloss = 0.f;
#pragma unroll
    for (int i = 0; i < 8; ++i) {
        int q = tid + i * 256;
        int tok = q >> 4, d4 = q & 15;
        int idx = Is[tok];
        float mv = mask[(size_t)(n0tk + tok) * NCB + c];
        float4 e4 = *(const float4*)(emb + ((size_t)c * MCODE + idx) * DIM + d4 * 4);
        float4 x4 = *(const float4*)(x + (size_t)(n0tk + tok) * (NCB * DIM) + c * DIM + d4 * 4);
        float qx = e4.x * mv, qy = e4.y * mv, qz = e4.z * mv, qw = e4.w * mv;
        float4 o;
        o.x = x4.x + (qx - x4.x);
        o.y = x4.y + (qy - x4.y);
        o.z = x4.z + (qz - x4.z);
        o.w = x4.w + (qw - x4.w);
        *(float4*)(outQ + (size_t)(n0tk + tok) * (NCB * DIM) + c * DIM + d4 * 4) = o;
        float dx = x4.x - qx, dy = x4.y - qy, dz = x4.z - qz, dw = x4.w - qw;
        lloss += dx * dx + dy * dy + dz * dz + dw * dw;
    }
#pragma unroll
    for (int off = 32; off > 0; off >>= 1) lloss += __shfl_xor(lloss, off);
    if ((tid & 63) == 0) wls[tid >> 6] = lloss;
    __syncthreads();
    if (tid == 0) {
        float s = wls[0] + wls[1] + wls[2] + wls[3];
        atomicAdd(lossSum, s);
    }
}

__global__ __launch_bounds__(256) void finalize_kernel(const int* __restrict__ counts,
                                                       const float* __restrict__ lossSum,
                                                       float* __restrict__ out) {
    __shared__ float wls[4];
    int tid = threadIdx.x;
    float s = 0.f;
#pragma unroll
    for (int i = 0; i < 8; ++i) {
        int j = tid + i * 256;
        float p = (float)counts[j] * (1.0f / 65536.0f);
        s += p * logf(p + 1e-10f);
    }
#pragma unroll
    for (int off = 32; off > 0; off >>= 1) s += __shfl_xor(s, off);
    if ((tid & 63) == 0) wls[tid >> 6] = s;
    __syncthreads();
    if (tid == 0) {
        float tot = wls[0] + wls[1] + wls[2] + wls[3];
        float L = *lossSum * (1.0f / (float)QST_SIZE);
        out[QST_SIZE + 0] = 0.25f * L;   // commitment_loss
        out[QST_SIZE + 1] = L;           // codebook_loss
        out[QST_SIZE + 2] = expf(-tot);  // perplexity
    }
}

extern "C" void kernel_launch(void* const* d_in, const int* in_sizes, int n_in,
                              void* d_out, int out_size, void* d_ws, size_t ws_size,
                              hipStream_t stream) {
    const float* x    = (const float*)d_in[0];
    const float* emb  = (const float*)d_in[1];
    const float* mask = (const float*)d_in[2];
    float* out = (float*)d_out;

    _Float16* ehf  = (_Float16*)((char*)d_ws + WS_EH);
    _Float16* elf  = (_Float16*)((char*)d_ws + WS_EL);
    float* d0p     = (float*)((char*)d_ws + WS_D0);
    int*   counts  = (int*)((char*)d_ws + WS_CNT);
    float* lossSum = (float*)((char*)d_ws + WS_LOSS);

    prep_kernel<<<dim3(8), dim3(256), 0, stream>>>(emb, ehf, elf, d0p, counts, lossSum);
    vq_main<<<dim3(NTOK / TOK_TILE, NCB), dim3(256), 0, stream>>>(
        x, emb, mask, ehf, elf, d0p, counts, lossSum, out, out + IDX_OFF);
    finalize_kernel<<<dim3(1), dim3(256), 0, stream>>>(counts, lossSum, out);
}